// Round 10
// baseline (134.963 us; speedup 1.0000x reference)
//
#include <hip/hip_runtime.h>
#include <math.h>

// SinkhornM round 11: MLP moved to the idle matrix pipe (f16 MFMA, fp32 accum).
//  - Per wave (64 rows): L1 = 2x mfma_f32_32x32x16_f16 (K pad 8->16),
//    L2 = 4x (K=32 in 2 steps), L3 = 2x (K=16). B-fragments (weights, f16)
//    staged once per block in per-lane fragment order -> 1 ds_read_b128 each.
//  - Layer transposes (C-layout -> A-layout) through per-wave-private LDS
//    (f16, padded strides for b128 alignment + bank spread). Same-wave DS
//    ordering guarantees write->read without barriers.
//  - Tail (tau/sigmoid/Sinkhorn) unchanged from R10 (fp32, folded).
//  - k-permutation invariance: any consistent A/B k-order cancels in the
//    MFMA contraction; C/D layout is the m74/m101-verified formula.
// Tripwires: WRITE_SIZE ~69632 KB; MfmaUtil > 0; absmax expected <= ~0.008.

#define QLOW  0.02f
#define QSPAN 0.96f
#define L2E   1.44269504088896f

typedef _Float16 half8 __attribute__((ext_vector_type(8)));
typedef float f32x16 __attribute__((ext_vector_type(16)));

__device__ __forceinline__ float frcp(float x) { return __builtin_amdgcn_rcpf(x); }

union H8u { half8 v; unsigned u[4]; uint4 q; };

__device__ __forceinline__ unsigned pkh(float a, float b) {
    union { _Float16 h[2]; unsigned u; } x;
    x.h[0] = (_Float16)a; x.h[1] = (_Float16)b;
    return x.u;
}

__global__ __launch_bounds__(256) void sinkhorn_fused(
    const float* __restrict__ margins,
    const float* __restrict__ W1, const float* __restrict__ b1,
    const float* __restrict__ W2, const float* __restrict__ b2,
    const float* __restrict__ W3, const float* __restrict__ b3,
    float* __restrict__ out, int n)
{
    // ---- block-shared weight fragments (f16, per-lane fragment order) ----
    __shared__ __align__(16) _Float16 B1h[64][8];     // W1: K pad 8->16, N=32
    __shared__ __align__(16) _Float16 B2h[2][64][8];  // W2: K=32 (2 steps), N pad 16->32
    __shared__ __align__(16) _Float16 B3h[64][8];     // W3: K=16, N pad 9->32
    __shared__ float sb1[32];
    __shared__ float sb2[32];                          // cols 16..31 = 0
    // ---- per-wave private transpose buffers ----
    __shared__ __align__(16) _Float16 H1h[4][64][40];  // stride 80B (16B-mult)
    __shared__ __align__(16) _Float16 H2h[4][64][24];  // stride 48B
    __shared__ __align__(16) float    Pf [4][64][12];  // stride 48B

    {
        const int t = threadIdx.x;
        for (int i = t; i < 512; i += 256) {           // B1 frags
            const int lane = i >> 3, e = i & 7;
            const int col = lane & 31, k = ((lane >> 5) << 3) + e;
            B1h[lane][e] = (_Float16)((k < 8) ? W1[k * 32 + col] : 0.0f);
        }
        for (int i = t; i < 1024; i += 256) {          // B2 frags
            const int s = i >> 9, j = i & 511;
            const int lane = j >> 3, e = j & 7;
            const int col = lane & 31, k = 16 * s + ((lane >> 5) << 3) + e;
            B2h[s][lane][e] = (_Float16)((col < 16) ? W2[k * 16 + col] : 0.0f);
        }
        for (int i = t; i < 512; i += 256) {           // B3 frags
            const int lane = i >> 3, e = i & 7;
            const int col = lane & 31, k = ((lane >> 5) << 3) + e;
            B3h[lane][e] = (_Float16)((col < 9) ? W3[k * 9 + col] : 0.0f);
        }
        if (t < 32) sb1[t] = b1[t];
        if (t < 32) sb2[t] = (t < 16) ? b2[t] : 0.0f;
    }
    __syncthreads();

    const int w = threadIdx.x >> 6;          // wave in block
    const int l = threadIdx.x & 63;          // lane
    const int c = l & 31;                    // fragment column
    const int wavebase = blockIdx.x * 256 + (w << 6);
    const int row = wavebase + l;            // this lane's output row

    // ---- load margins: own row + tile-1 partner row ----
    const float4* __restrict__ m4 = (const float4*)margins;
    const float4 a0q = m4[row * 2 + 0];
    const float4 a1q = m4[row * 2 + 1];
    float m[8];
    m[0] = a0q.x; m[1] = a0q.y; m[2] = a0q.z; m[3] = a0q.w;
    m[4] = a1q.x; m[5] = a1q.y; m[6] = a1q.z; m[7] = a1q.w;

    const int row2 = wavebase + 32 + c;      // rows 32..63 of this wave
    const float4 b0q = m4[row2 * 2 + 0];
    const float4 b1q = m4[row2 * 2 + 1];

    const bool lo32 = (l < 32);

    // ---- A1 fragments: lanes<32 hold k=0..7 (real), lanes>=32 k=8..15 (pad=0)
    H8u a1t0, a1t1;
    a1t0.u[0] = lo32 ? pkh(m[0], m[1]) : 0u;
    a1t0.u[1] = lo32 ? pkh(m[2], m[3]) : 0u;
    a1t0.u[2] = lo32 ? pkh(m[4], m[5]) : 0u;
    a1t0.u[3] = lo32 ? pkh(m[6], m[7]) : 0u;
    a1t1.u[0] = lo32 ? pkh(b0q.x, b0q.y) : 0u;
    a1t1.u[1] = lo32 ? pkh(b0q.z, b0q.w) : 0u;
    a1t1.u[2] = lo32 ? pkh(b1q.x, b1q.y) : 0u;
    a1t1.u[3] = lo32 ? pkh(b1q.z, b1q.w) : 0u;

    // ---- layer 1 MFMA: H1(64x32) ----
    const half8 b1v = *reinterpret_cast<const half8*>(&B1h[l][0]);
    f32x16 C0 = {}, C1 = {};
    C0 = __builtin_amdgcn_mfma_f32_32x32x16_f16(a1t0.v, b1v, C0, 0, 0, 0);
    C1 = __builtin_amdgcn_mfma_f32_32x32x16_f16(a1t1.v, b1v, C1, 0, 0, 0);

    // bias + relu + transpose to row-major f16 (per-wave private region)
    {
        const float b1c = sb1[c];
#pragma unroll
        for (int r = 0; r < 16; ++r) {
            const int rowv = (r & 3) + 8 * (r >> 2) + ((l >> 5) << 2);
            H1h[w][rowv][c]      = (_Float16)fmaxf(C0[r] + b1c, 0.0f);
            H1h[w][rowv + 32][c] = (_Float16)fmaxf(C1[r] + b1c, 0.0f);
        }
    }

    // ---- layer 2: A-frags from H1h, 2 M-tiles x 2 K-steps ----
    half8 A2[2][2];
#pragma unroll
    for (int T = 0; T < 2; ++T)
#pragma unroll
        for (int s = 0; s < 2; ++s)
            A2[T][s] = *reinterpret_cast<const half8*>(
                &H1h[w][(l & 31) + 32 * T][16 * s + ((l >> 5) << 3)]);

    const half8 b2v0 = *reinterpret_cast<const half8*>(&B2h[0][l][0]);
    const half8 b2v1 = *reinterpret_cast<const half8*>(&B2h[1][l][0]);
    f32x16 D0 = {}, D1 = {};
    D0 = __builtin_amdgcn_mfma_f32_32x32x16_f16(A2[0][0], b2v0, D0, 0, 0, 0);
    D0 = __builtin_amdgcn_mfma_f32_32x32x16_f16(A2[0][1], b2v1, D0, 0, 0, 0);
    D1 = __builtin_amdgcn_mfma_f32_32x32x16_f16(A2[1][0], b2v0, D1, 0, 0, 0);
    D1 = __builtin_amdgcn_mfma_f32_32x32x16_f16(A2[1][1], b2v1, D1, 0, 0, 0);

    // bias + relu + transpose (only real cols < 16)
    if (c < 16) {
        const float b2c = sb2[c];
#pragma unroll
        for (int r = 0; r < 16; ++r) {
            const int rowv = (r & 3) + 8 * (r >> 2) + ((l >> 5) << 2);
            H2h[w][rowv][c]      = (_Float16)fmaxf(D0[r] + b2c, 0.0f);
            H2h[w][rowv + 32][c] = (_Float16)fmaxf(D1[r] + b2c, 0.0f);
        }
    }

    // ---- layer 3: pars(64x9), K=16 single step ----
    half8 A3[2];
#pragma unroll
    for (int T = 0; T < 2; ++T)
        A3[T] = *reinterpret_cast<const half8*>(
            &H2h[w][(l & 31) + 32 * T][(l >> 5) << 3]);

    const half8 b3v = *reinterpret_cast<const half8*>(&B3h[l][0]);
    f32x16 P0 = {}, P1 = {};
    P0 = __builtin_amdgcn_mfma_f32_32x32x16_f16(A3[0], b3v, P0, 0, 0, 0);
    P1 = __builtin_amdgcn_mfma_f32_32x32x16_f16(A3[1], b3v, P1, 0, 0, 0);

    // transpose pars back to one-row-per-lane (cols < 9 real)
    if (c < 9) {
#pragma unroll
        for (int r = 0; r < 16; ++r) {
            const int rowv = (r & 3) + 8 * (r >> 2) + ((l >> 5) << 2);
            Pf[w][rowv][c]      = P0[r];
            Pf[w][rowv + 32][c] = P1[r];
        }
    }

    const float4* pr = reinterpret_cast<const float4*>(&Pf[w][l][0]);
    const float4 pA = pr[0];
    const float4 pB = pr[1];
    const float pC = Pf[w][l][8];

    const float p0 = pA.x + b3[0], p1 = pA.y + b3[1];
    const float p2 = pA.z + b3[2], p3 = pA.w + b3[3];
    const float p4 = pB.x + b3[4], p5 = pB.y + b3[5];
    const float p6 = pB.z + b3[6], p7 = pB.w + b3[7];
    const float p8v = pC + b3[8];

    // ---- tau in exp2/log2 space (fp32, unchanged from R10) ----
    const float l0 = p0 * L2E, l1 = p1 * L2E;
    const float l2 = p2 * L2E, l3 = p3 * L2E;

    const float a00 = exp2f(l0), a01 = exp2f(l1);
    const float a10 = exp2f(l2), a11 = exp2f(l3);
    const float h01 = (l0 + l1) * 0.5f, h23 = (l2 + l3) * 0.5f;
    const float a02 = exp2f(h01);
    const float a12 = exp2f(h23);
    const float a20 = exp2f((l0 + l2) * 0.5f);
    const float a21 = exp2f((l1 + l3) * 0.5f);
    const float a22 = exp2f((h01 + h23) * 0.5f);

    const float s4 = fmaf(QSPAN, frcp(1.0f + exp2f(-L2E * p4)), QLOW);
    const float s5 = fmaf(QSPAN, frcp(1.0f + exp2f(-L2E * p5)), QLOW);
    const float s6 = fmaf(QSPAN, frcp(1.0f + exp2f(-L2E * p6)), QLOW);
    const float s7 = fmaf(QSPAN, frcp(1.0f + exp2f(-L2E * p7)), QLOW);

    const float rm0 = m[0] * s4, rm1 = m[1] * s5, rm2 = m[2];
    const float cm0 = m[3] * s6, cm1 = m[4] * s7, cm2 = m[5];

    float t0 = (a00 + a01) + a02;   // A @ v with v = 1
    float t1 = (a10 + a11) + a12;
    float t2 = (a20 + a21) + a22;

    float zp0, zp1, zp2, wp0, wp1, wp2;
#pragma unroll
    for (int it = 0; it < 10; ++it) {
        zp0 = rm0 * frcp(t0);
        zp1 = rm1 * frcp(t1);
        zp2 = rm2 * frcp(t2);
        const float q0 = fmaf(a20, zp2, fmaf(a10, zp1, a00 * zp0));
        const float q1 = fmaf(a21, zp2, fmaf(a11, zp1, a01 * zp0));
        const float q2 = fmaf(a22, zp2, fmaf(a12, zp1, a02 * zp0));
        wp0 = cm0 * frcp(q0);
        wp1 = cm1 * frcp(q1);
        wp2 = cm2 * frcp(q2);
        if (it < 9) {
            t0 = fmaf(a02, wp2, fmaf(a01, wp1, a00 * wp0));
            t1 = fmaf(a12, wp2, fmaf(a11, wp1, a10 * wp0));
            t2 = fmaf(a22, wp2, fmaf(a21, wp1, a20 * wp0));
        }
    }

    const float A0f = zp0 * a00 * wp0, A1f = zp0 * a01 * wp1, A2f = zp0 * a02 * wp2;
    const float A3f = zp1 * a10 * wp0, A4f = zp1 * a11 * wp1, A5f = zp1 * a12 * wp2;
    const float A6f = zp2 * a20 * wp0, A7f = zp2 * a21 * wp1, A8f = zp2 * a22 * wp2;

    const float um0 = m[0] - rm0;
    const float um1 = m[1] - rm1;
    const float uf0 = m[3] - cm0;
    const float uf1 = m[4] - cm1;

    float4* __restrict__ o4 = (float4*)out;
    float* __restrict__ oV = out + (size_t)n * 16;

    o4[row * 4 + 0] = make_float4(A0f, A1f, A2f, um0);
    o4[row * 4 + 1] = make_float4(A3f, A4f, A5f, um1);
    o4[row * 4 + 2] = make_float4(A6f, A7f, A8f, 0.0f);
    o4[row * 4 + 3] = make_float4(uf0, uf1, 0.0f, 0.0f);
    oV[row] = exp2f(p8v * L2E);
}

extern "C" void kernel_launch(void* const* d_in, const int* in_sizes, int n_in,
                              void* d_out, int out_size, void* d_ws, size_t ws_size,
                              hipStream_t stream) {
    const float* margins = (const float*)d_in[0];
    const float* W1 = (const float*)d_in[1];
    const float* b1 = (const float*)d_in[2];
    const float* W2 = (const float*)d_in[3];
    const float* b2 = (const float*)d_in[4];
    const float* W3 = (const float*)d_in[5];
    const float* b3 = (const float*)d_in[6];

    const int n = in_sizes[0] / 8;       // 1,048,576 rows
    dim3 block(256), grid(n / 256);      // 1 row per thread

    sinkhorn_fused<<<grid, block, 0, stream>>>(margins, W1, b1, W2, b2, W3, b3,
                                               (float*)d_out, n);
}

// Round 11
// 127.719 us; speedup vs baseline: 1.0567x; 1.0567x over previous
//
#include <hip/hip_runtime.h>
#include <math.h>

// SinkhornM round 12 = R8 skeleton (47.2us best: s_load weights, packed MLP,
// R=2 interleaved tail) with a denominator-cleared Sinkhorn:
//   p~i = prod_{k!=i} t_k ; D = t0*t1*t2
//   e_i = rm_i*p~i (= u_i*D) ; N_j = sum_i a_ij e_i (= q_j*D)
//   f_j = cm_j*rcp(N_j) (= v_j/D) ; t'_i = D * sum_j a_ij f_j
// EXACT same t-sequence as the verified R3/R8 tail (D is kept, not dropped),
// but 3 rcp/iter instead of 6 and one rcp-latency stage per iter instead of
// two. Epilogue: A_ij = a_ij*e_i*f_j (D cancels, no extra rcp).
// Sigmoid rcps paired via common denominator (4 -> 2).
// Trans ops/row: 78 -> 46. Theory: the 47us plateau is trans-pipe +
// rcp-chain bound (the one invariant across R0-R11).
// Tripwires: WRITE_SIZE ~69632 KB (no spill); absmax <= 0.0078 (harness
// accepted 0.0078125 in R11; expect ~0.004).

#define QLOW  0.02f
#define QSPAN 0.96f
#define L2E   1.44269504088896f

constexpr int R = 2;

typedef __attribute__((ext_vector_type(2))) float f32x2;

__device__ __forceinline__ float frcp(float x) { return __builtin_amdgcn_rcpf(x); }
__device__ __forceinline__ f32x2 pfma(f32x2 a, f32x2 b, f32x2 c) {
    return __builtin_elementwise_fma(a, b, c);
}

__global__ __launch_bounds__(256, 2) void sinkhorn_fused(
    const float* __restrict__ margins,
    const float* __restrict__ W1, const float* __restrict__ b1,
    const float* __restrict__ W2, const float* __restrict__ b2,
    const float* __restrict__ W3, const float* __restrict__ b3,
    float* __restrict__ out, int n)
{
    const int tid  = blockIdx.x * blockDim.x + threadIdx.x;
    const int lane = tid & 63;
    const int base = (tid >> 6) * (64 * R) + lane;  // rows base, base+64

    const float4* __restrict__ m4 = (const float4*)margins;

    float m[R][8];
#pragma unroll
    for (int r = 0; r < R; ++r) {
        const int row = base + 64 * r;
        const float4 a0 = m4[row * 2 + 0];
        const float4 a1 = m4[row * 2 + 1];
        m[r][0] = a0.x; m[r][1] = a0.y; m[r][2] = a0.z; m[r][3] = a0.w;
        m[r][4] = a1.x; m[r][5] = a1.y; m[r][6] = a1.z; m[r][7] = a1.w;
    }

    const f32x2* __restrict__ W1v = (const f32x2*)W1;  // (8,32) -> [k][16 pairs]
    const f32x2* __restrict__ W2v = (const f32x2*)W2;  // (32,16) -> [k][8 pairs]
    const f32x2* __restrict__ b1v = (const f32x2*)b1;
    const f32x2* __restrict__ b2v = (const f32x2*)b2;

    // ---- layer 1: h1 = relu(m @ W1 + b1), 32 wide = 16 pairs ----
    f32x2 h1[R][16];
#pragma unroll
    for (int j = 0; j < 16; ++j) {
        const f32x2 bb = b1v[j];
#pragma unroll
        for (int r = 0; r < R; ++r) h1[r][j] = bb;
    }
#pragma unroll
    for (int k = 0; k < 8; ++k) {
        f32x2 mk[R];
#pragma unroll
        for (int r = 0; r < R; ++r) { mk[r].x = m[r][k]; mk[r].y = m[r][k]; }
#pragma unroll
        for (int j = 0; j < 16; ++j) {
            const f32x2 w = W1v[k * 16 + j];
#pragma unroll
            for (int r = 0; r < R; ++r) h1[r][j] = pfma(mk[r], w, h1[r][j]);
        }
    }
    const f32x2 zero2 = {0.0f, 0.0f};
#pragma unroll
    for (int j = 0; j < 16; ++j)
#pragma unroll
        for (int r = 0; r < R; ++r)
            h1[r][j] = __builtin_elementwise_max(h1[r][j], zero2);

    // ---- layer 2: h2 = relu(h1 @ W2 + b2), 16 wide = 8 pairs ----
    f32x2 h2[R][8];
#pragma unroll
    for (int j = 0; j < 8; ++j) {
        const f32x2 bb = b2v[j];
#pragma unroll
        for (int r = 0; r < R; ++r) h2[r][j] = bb;
    }
#pragma unroll
    for (int k = 0; k < 32; ++k) {
        f32x2 hk[R];
#pragma unroll
        for (int r = 0; r < R; ++r) {
            const float s = (k & 1) ? h1[r][k >> 1].y : h1[r][k >> 1].x;
            hk[r].x = s; hk[r].y = s;
        }
#pragma unroll
        for (int j = 0; j < 8; ++j) {
            const f32x2 w = W2v[k * 8 + j];
#pragma unroll
            for (int r = 0; r < R; ++r) h2[r][j] = pfma(hk[r], w, h2[r][j]);
        }
    }
#pragma unroll
    for (int j = 0; j < 8; ++j)
#pragma unroll
        for (int r = 0; r < R; ++r)
            h2[r][j] = __builtin_elementwise_max(h2[r][j], zero2);

    // ---- layer 3: p = h2 @ W3 + b3, 9 wide = 4 pairs + 1 scalar ----
    f32x2 p01[R], p23[R], p45[R], p67[R];
    float p8[R];
    {
        const f32x2 b01 = {b3[0], b3[1]};
        const f32x2 b23 = {b3[2], b3[3]};
        const f32x2 b45 = {b3[4], b3[5]};
        const f32x2 b67 = {b3[6], b3[7]};
        const float b8  = b3[8];
#pragma unroll
        for (int r = 0; r < R; ++r) {
            p01[r] = b01; p23[r] = b23; p45[r] = b45; p67[r] = b67; p8[r] = b8;
        }
    }
#pragma unroll
    for (int k = 0; k < 16; ++k) {
        const f32x2 w01 = {W3[k * 9 + 0], W3[k * 9 + 1]};
        const f32x2 w23 = {W3[k * 9 + 2], W3[k * 9 + 3]};
        const f32x2 w45 = {W3[k * 9 + 4], W3[k * 9 + 5]};
        const f32x2 w67 = {W3[k * 9 + 6], W3[k * 9 + 7]};
        const float w8  = W3[k * 9 + 8];
#pragma unroll
        for (int r = 0; r < R; ++r) {
            const float s = (k & 1) ? h2[r][k >> 1].y : h2[r][k >> 1].x;
            f32x2 hb; hb.x = s; hb.y = s;
            p01[r] = pfma(hb, w01, p01[r]);
            p23[r] = pfma(hb, w23, p23[r]);
            p45[r] = pfma(hb, w45, p45[r]);
            p67[r] = pfma(hb, w67, p67[r]);
            p8[r]  = fmaf(s, w8, p8[r]);
        }
    }

    // ---- per-row tail state (both rows live; minimal set; same as R8) ----
    float aa[R][9];
    float rm[R][3], cm[R][3];
    float t0_[R], t1_[R], t2_[R];
    float Vv[R];

#pragma unroll
    for (int r = 0; r < R; ++r) {
        const float l0 = p01[r].x * L2E, l1 = p01[r].y * L2E;
        const float l2 = p23[r].x * L2E, l3 = p23[r].y * L2E;

        const float a00 = exp2f(l0), a01 = exp2f(l1);
        const float a10 = exp2f(l2), a11 = exp2f(l3);
        const float h01 = (l0 + l1) * 0.5f, h23 = (l2 + l3) * 0.5f;
        const float a02 = exp2f(h01);
        const float a12 = exp2f(h23);
        const float a20 = exp2f((l0 + l2) * 0.5f);
        const float a21 = exp2f((l1 + l3) * 0.5f);
        const float a22 = exp2f((h01 + h23) * 0.5f);
        aa[r][0] = a00; aa[r][1] = a01; aa[r][2] = a02;
        aa[r][3] = a10; aa[r][4] = a11; aa[r][5] = a12;
        aa[r][6] = a20; aa[r][7] = a21; aa[r][8] = a22;

        // paired sigmoids: one rcp per (s4,s5) and (s6,s7)
        const float ea4 = exp2f(-L2E * p45[r].x);
        const float ea5 = exp2f(-L2E * p45[r].y);
        const float d4 = 1.0f + ea4, d5 = 1.0f + ea5;
        const float r45 = frcp(d4 * d5);
        const float s4 = fmaf(QSPAN, d5 * r45, QLOW);
        const float s5 = fmaf(QSPAN, d4 * r45, QLOW);

        const float ea6 = exp2f(-L2E * p67[r].x);
        const float ea7 = exp2f(-L2E * p67[r].y);
        const float d6 = 1.0f + ea6, d7 = 1.0f + ea7;
        const float r67 = frcp(d6 * d7);
        const float s6 = fmaf(QSPAN, d7 * r67, QLOW);
        const float s7 = fmaf(QSPAN, d6 * r67, QLOW);

        rm[r][0] = m[r][0] * s4; rm[r][1] = m[r][1] * s5; rm[r][2] = m[r][2];
        cm[r][0] = m[r][3] * s6; cm[r][1] = m[r][4] * s7; cm[r][2] = m[r][5];

        t0_[r] = (a00 + a01) + a02;   // A @ v with v = 1
        t1_[r] = (a10 + a11) + a12;
        t2_[r] = (a20 + a21) + a22;

        Vv[r] = exp2f(p8[r] * L2E);
    }

    // ---- denominator-cleared Sinkhorn, R=2 interleaved ----
    // e_i = u_i*D, f_j = v_j/D; t' = D * (A f) reproduces the exact t-seq.
    float e0_[R], e1_[R], e2_[R], f0_[R], f1_[R], f2_[R];
#pragma unroll
    for (int it = 0; it < 10; ++it) {
#pragma unroll
        for (int r = 0; r < R; ++r) {
            const float p12 = t1_[r] * t2_[r];
            const float p02 = t0_[r] * t2_[r];
            const float p01v = t0_[r] * t1_[r];
            const float e0 = rm[r][0] * p12;
            const float e1 = rm[r][1] * p02;
            const float e2 = rm[r][2] * p01v;
            const float N0 = fmaf(aa[r][6], e2, fmaf(aa[r][3], e1, aa[r][0] * e0));
            const float N1 = fmaf(aa[r][7], e2, fmaf(aa[r][4], e1, aa[r][1] * e0));
            const float N2 = fmaf(aa[r][8], e2, fmaf(aa[r][5], e1, aa[r][2] * e0));
            const float f0 = cm[r][0] * frcp(N0);
            const float f1 = cm[r][1] * frcp(N1);
            const float f2 = cm[r][2] * frcp(N2);
            e0_[r] = e0; e1_[r] = e1; e2_[r] = e2;
            f0_[r] = f0; f1_[r] = f1; f2_[r] = f2;
            if (it < 9) {
                const float D = t0_[r] * p12;
                const float S0 = fmaf(aa[r][2], f2, fmaf(aa[r][1], f1, aa[r][0] * f0));
                const float S1 = fmaf(aa[r][5], f2, fmaf(aa[r][4], f1, aa[r][3] * f0));
                const float S2 = fmaf(aa[r][8], f2, fmaf(aa[r][7], f1, aa[r][6] * f0));
                t0_[r] = D * S0; t1_[r] = D * S1; t2_[r] = D * S2;
            }
        }
    }

    float4* __restrict__ o4 = (float4*)out;
    float* __restrict__ oV = out + (size_t)n * 16;

#pragma unroll
    for (int r = 0; r < R; ++r) {
        const int row = base + 64 * r;
        const float e0 = e0_[r], e1 = e1_[r], e2 = e2_[r];
        const float f0 = f0_[r], f1 = f1_[r], f2 = f2_[r];

        // A_ij = a_ij * e_i * f_j  (u_i = e_i/D, v_j = D*f_j; D cancels)
        const float g0 = aa[r][0] * e0, g1 = aa[r][1] * e0, g2 = aa[r][2] * e0;
        const float g3 = aa[r][3] * e1, g4 = aa[r][4] * e1, g5 = aa[r][5] * e1;
        const float g6 = aa[r][6] * e2, g7 = aa[r][7] * e2, g8 = aa[r][8] * e2;

        const float A0f = g0 * f0, A1f = g1 * f1, A2f = g2 * f2;
        const float A3f = g3 * f0, A4f = g4 * f1, A5f = g5 * f2;
        const float A6f = g6 * f0, A7f = g7 * f1, A8f = g8 * f2;

        const float um0 = m[r][0] - rm[r][0];
        const float um1 = m[r][1] - rm[r][1];
        const float uf0 = m[r][3] - cm[r][0];
        const float uf1 = m[r][4] - cm[r][1];

        o4[row * 4 + 0] = make_float4(A0f, A1f, A2f, um0);
        o4[row * 4 + 1] = make_float4(A3f, A4f, A5f, um1);
        o4[row * 4 + 2] = make_float4(A6f, A7f, A8f, 0.0f);
        o4[row * 4 + 3] = make_float4(uf0, uf1, 0.0f, 0.0f);
        oV[row] = Vv[r];
    }
}

extern "C" void kernel_launch(void* const* d_in, const int* in_sizes, int n_in,
                              void* d_out, int out_size, void* d_ws, size_t ws_size,
                              hipStream_t stream) {
    const float* margins = (const float*)d_in[0];
    const float* W1 = (const float*)d_in[1];
    const float* b1 = (const float*)d_in[2];
    const float* W2 = (const float*)d_in[3];
    const float* b2 = (const float*)d_in[4];
    const float* W3 = (const float*)d_in[5];
    const float* b3 = (const float*)d_in[6];

    const int n = in_sizes[0] / 8;       // 1,048,576 rows
    const int threads = n / R;
    dim3 block(256), grid(threads / 256);

    sinkhorn_fused<<<grid, block, 0, stream>>>(margins, W1, b1, W2, b2, W3, b3,
                                               (float*)d_out, n);
}